// Round 2
// baseline (6382.867 us; speedup 1.0000x reference)
//
#include <hip/hip_runtime.h>
#include <math.h>

// ---------------------------------------------------------------------------
// LSV Monte Carlo, round 2: all weights staged in LDS (broadcast ds_read),
// h1 activations as packed bf16 chunks (conflict-free b64), branchless
// per-wave column slices, float2 packed FMA (v_pk_fma_f32), fast transcendentals.
// 256 blocks x 1024 threads; lane = path (64 paths/block), 16 waves split the
// 100 layer-2 columns (4 waves x7 + 12 waves x6) and the 84 (mat,strike) pairs.
// ---------------------------------------------------------------------------

#define MC      16384
#define NSTEP   96
#define NPATH   64
#define NWAVE   16
#define BLOCK   1024
#define NGROUP  256
#define NPAIR   84

typedef float f2 __attribute__((ext_vector_type(2)));

struct __align__(16) Lds {
    float        W2T[100][100];      // [j][k]  40000 B
    unsigned int h1c[25][64][2];     // chunk c: k=4c..4c+3 as 4 packed bf16, 12800 B
    float        red[NWAVE][64];     // 4096 B
    float        vhW1[4][2][20];     // 640
    float        vhb1[4][20];        // 320
    float        vhW2T[4][21][20];   // [m][s][j] 3360
    float        vhb2[4][21];        // 336
    float        vdW1[20], vdb1[20], vdW2[20];   // 240
    float        vvW1[20], vvb1[20], vvW2[20];   // 240
    float        svW1[3][100];       // 1200
    float        svb1[100];          // 400
    float        svb2[100];          // 400
    float        svW3[100];          // 400
    float        strikes[21];        // 84
};  // total 64516 B

__device__ __forceinline__ unsigned int bf16rne(float x) {
    unsigned int u = __float_as_uint(x);
    return (u + 0x7FFFu + ((u >> 16) & 1u)) >> 16;
}

__device__ __forceinline__ float sp(float x) {   // softplus, fast
    return fmaxf(x, 0.f) + __logf(1.f + __expf(-fabsf(x)));
}

template<int JCNT>
__device__ __forceinline__ float p2_dot(const Lds* L, int lane, int j0) {
    f2 acc[JCNT];
#pragma unroll
    for (int jj = 0; jj < JCNT; jj++) { acc[jj].x = 0.f; acc[jj].y = 0.f; }
#pragma unroll 5
    for (int c = 0; c < 25; c++) {
        const uint2 hu = *reinterpret_cast<const uint2*>(&L->h1c[c][lane][0]); // ds_read_b64
        f2 h01, h23;
        h01.x = __uint_as_float(hu.x << 16);
        h01.y = __uint_as_float(hu.x & 0xFFFF0000u);
        h23.x = __uint_as_float(hu.y << 16);
        h23.y = __uint_as_float(hu.y & 0xFFFF0000u);
#pragma unroll
        for (int jj = 0; jj < JCNT; jj++) {
            const float4 wv = *reinterpret_cast<const float4*>(&L->W2T[j0 + jj][4 * c]); // b128 broadcast
            f2 w01, w23;
            w01.x = wv.x; w01.y = wv.y;
            w23.x = wv.z; w23.y = wv.w;
            acc[jj] += h01 * w01;   // v_pk_fma_f32
            acc[jj] += h23 * w23;
        }
    }
    float pout = 0.f;
#pragma unroll
    for (int jj = 0; jj < JCNT; jj++) {
        const int j = j0 + jj;
        const float pre = acc[jj].x + acc[jj].y + L->svb2[j];
        pout += fmaxf(pre, 0.f) * L->svW3[j];
    }
    return pout;
}

__global__ __launch_bounds__(BLOCK)
void lsv_sim(const float* __restrict__ S0p,   const float* __restrict__ ratep,
             const float* __restrict__ z,     const float* __restrict__ zzg,
             const float* __restrict__ strikesg,
             const float* __restrict__ v0p,   const float* __restrict__ rhop,
             const float* __restrict__ svW1,  const float* __restrict__ svb1,
             const float* __restrict__ svW2,  const float* __restrict__ svb2,
             const float* __restrict__ svW3,  const float* __restrict__ svb3,
             const float* __restrict__ vhW1,  const float* __restrict__ vhb1,
             const float* __restrict__ vhW2,  const float* __restrict__ vhb2,
             const float* __restrict__ vdW1,  const float* __restrict__ vdb1,
             const float* __restrict__ vdW2,  const float* __restrict__ vdb2,
             const float* __restrict__ vvW1,  const float* __restrict__ vvb1,
             const float* __restrict__ vvW2,  const float* __restrict__ vvb2,
             const int*   __restrict__ mats,
             float* __restrict__ psum, float* __restrict__ psq)
{
    __shared__ Lds lds;
    Lds* L = &lds;
    const int tid  = threadIdx.x;
    const int lane = tid & 63;
    const int w    = __builtin_amdgcn_readfirstlane(tid >> 6);
    const int gpath = blockIdx.x * NPATH + lane;

    // ---- stage all params into LDS (once; amortized over 96 steps) --------
    for (int e = tid; e < 10000; e += BLOCK) { int j = e / 100, k = e - 100 * j; L->W2T[j][k] = svW2[k * 100 + j]; }
    for (int e = tid; e < 1680;  e += BLOCK) { int m = e / 420, r = e - m * 420; int s = r / 20, j = r - 20 * s;
                                               L->vhW2T[m][s][j] = vhW2[m * 420 + j * 21 + s]; }
    for (int e = tid; e < 160; e += BLOCK) ((float*)L->vhW1)[e] = vhW1[e];
    for (int e = tid; e < 80;  e += BLOCK) ((float*)L->vhb1)[e] = vhb1[e];
    for (int e = tid; e < 84;  e += BLOCK) ((float*)L->vhb2)[e] = vhb2[e];
    for (int e = tid; e < 20;  e += BLOCK) {
        L->vdW1[e] = vdW1[e]; L->vdb1[e] = vdb1[e]; L->vdW2[e] = vdW2[e];
        L->vvW1[e] = vvW1[e]; L->vvb1[e] = vvb1[e]; L->vvW2[e] = vvW2[e];
    }
    for (int e = tid; e < 300; e += BLOCK) ((float*)L->svW1)[e] = svW1[e];
    for (int e = tid; e < 100; e += BLOCK) { L->svb1[e] = svb1[e]; L->svb2[e] = svb2[e]; L->svW3[e] = svW3[e]; }
    for (int e = tid; e < 21;  e += BLOCK) L->strikes[e] = strikesg[e];

    // ---- uniform setup -----------------------------------------------------
    const float rate  = ratep[0];
    const float S0    = S0p[0];
    const float rho_t = tanhf(rhop[0]);
    const float srho  = sqrtf(1.f - rho_t * rho_t);
    const float b3    = svb3[0];
    const float vdb2s = vdb2[0];
    const float vvb2s = vvb2[0];
    int matr[4];
#pragma unroll
    for (int k = 0; k < 4; k++) matr[k] = mats[k];

    const int j0 = (w < 4) ? (7 * w) : (6 * w + 4);
    const int m    = w >> 2;
    const int q4   = w & 3;
    const int ss0  = (q4 == 0) ? 0 : (6 + 5 * (q4 - 1));
    const int scnt = (q4 == 0) ? 6 : 5;

    __syncthreads();   // staging done

    float Karr[6];
#pragma unroll
    for (int si = 0; si < 6; si++) Karr[si] = L->strikes[ss0 + ((si < scnt) ? si : 0)];

    // ---- per-path state (identical in all 16 waves; lane = path) ----------
    float Slog = __logf(S0);
    float S    = __expf(Slog);
    float V    = (1.f / (1.f + __expf(-v0p[0]))) * 0.5f;
    float cv[6];
#pragma unroll
    for (int si = 0; si < 6; si++) cv[si] = 0.f;

    const float* zrow  = z   + (size_t)gpath * NSTEP;
    const float* zzrow = zzg + (size_t)gpath * NSTEP;

    for (int i = 0; i < NSTEP; i++) {
        // prefetch this step's normals early (in flight across P1/P2)
        const float zi  = zrow[i];
        const float zzi = zzrow[i];

        const float t0    = (float)i       / 365.0f;
        const float t1    = (float)(i + 1) / 365.0f;
        const float h     = t1 - t0;
        const float sqh   = sqrtf(h);
        const float disc0 = __expf(-rate * t0);
        const float disc1 = __expf(-rate * t1);
        const int   day   = i + 1;
        int idx = 0;
        while (idx < 3 && day > matr[idx]) idx++;
        const bool im = (day == matr[idx]);

        // ---- P1: s_vol layer 1 -> packed bf16 chunks in LDS ---------------
        {
            int clist[2]; int cn = 1; clist[0] = w;
            if (w < 9) { clist[1] = w + 16; cn = 2; }
            for (int ci = 0; ci < cn; ci++) {
                const int c = clist[ci];
                const float4 wa = *reinterpret_cast<const float4*>(&L->svW1[0][4 * c]);
                const float4 wb = *reinterpret_cast<const float4*>(&L->svW1[1][4 * c]);
                const float4 wc = *reinterpret_cast<const float4*>(&L->svW1[2][4 * c]);
                const float4 bb = *reinterpret_cast<const float4*>(&L->svb1[4 * c]);
                const float h0 = fmaxf(t0 * wa.x + Slog * wb.x + V * wc.x + bb.x, 0.f);
                const float h1 = fmaxf(t0 * wa.y + Slog * wb.y + V * wc.y + bb.y, 0.f);
                const float h2 = fmaxf(t0 * wa.z + Slog * wb.z + V * wc.z + bb.z, 0.f);
                const float h3 = fmaxf(t0 * wa.w + Slog * wb.w + V * wc.w + bb.w, 0.f);
                const unsigned int p0 = bf16rne(h0) | (bf16rne(h1) << 16);
                const unsigned int p1 = bf16rne(h2) | (bf16rne(h3) << 16);
                *reinterpret_cast<uint2*>(&L->h1c[c][lane][0]) = make_uint2(p0, p1); // ds_write_b64
            }
        }
        __syncthreads();

        // ---- P2: layer 2 j-slice + layer-3 partial ------------------------
        float pout;
        if (w < 4) pout = p2_dot<7>(L, lane, j0);
        else       pout = p2_dot<6>(L, lane, j0);
        L->red[w][lane] = pout;

        // ---- P3: vanilla hedge for (m, strike-slice), uses Slog_old -------
        float h1vh[20];
#pragma unroll
        for (int jq = 0; jq < 5; jq++) {
            const float4 wt = *reinterpret_cast<const float4*>(&L->vhW1[m][0][4 * jq]);
            const float4 ws = *reinterpret_cast<const float4*>(&L->vhW1[m][1][4 * jq]);
            const float4 bb = *reinterpret_cast<const float4*>(&L->vhb1[m][4 * jq]);
            h1vh[4 * jq + 0] = fmaxf(t0 * wt.x + Slog * ws.x + bb.x, 0.f);
            h1vh[4 * jq + 1] = fmaxf(t0 * wt.y + Slog * ws.y + bb.y, 0.f);
            h1vh[4 * jq + 2] = fmaxf(t0 * wt.z + Slog * ws.z + bb.z, 0.f);
            h1vh[4 * jq + 3] = fmaxf(t0 * wt.w + Slog * ws.w + bb.w, 0.f);
        }
        float cvf[6];
#pragma unroll
        for (int si = 0; si < 6; si++) {
            if (si < scnt) {
                const int s = ss0 + si;
                float a = L->vhb2[m][s];
#pragma unroll
                for (int jq = 0; jq < 5; jq++) {
                    const float4 wr = *reinterpret_cast<const float4*>(&L->vhW2T[m][s][4 * jq]);
                    a += h1vh[4 * jq + 0] * wr.x + h1vh[4 * jq + 1] * wr.y
                       + h1vh[4 * jq + 2] * wr.z + h1vh[4 * jq + 3] * wr.w;
                }
                cvf[si] = sp(a);
            } else cvf[si] = 0.f;
        }
        __syncthreads();

        // ---- P4: finish the step (redundant in every wave) ----------------
        float sum = 0.f;
#pragma unroll
        for (int ww = 0; ww < NWAVE; ww++) sum += L->red[ww][lane];
        const float pd = sp(sum + b3);

        const float dW = sqh * zi;
        const float dB = rho_t * dW + srho * sqh * zzi;

        float vd = vdb2s, vv = vvb2s;
#pragma unroll
        for (int jq = 0; jq < 5; jq++) {
            const float4 a1 = *reinterpret_cast<const float4*>(&L->vdW1[4 * jq]);
            const float4 b1 = *reinterpret_cast<const float4*>(&L->vdb1[4 * jq]);
            const float4 a2 = *reinterpret_cast<const float4*>(&L->vdW2[4 * jq]);
            vd += fmaxf(V * a1.x + b1.x, 0.f) * a2.x;
            vd += fmaxf(V * a1.y + b1.y, 0.f) * a2.y;
            vd += fmaxf(V * a1.z + b1.z, 0.f) * a2.z;
            vd += fmaxf(V * a1.w + b1.w, 0.f) * a2.w;
            const float4 c1 = *reinterpret_cast<const float4*>(&L->vvW1[4 * jq]);
            const float4 d1 = *reinterpret_cast<const float4*>(&L->vvb1[4 * jq]);
            const float4 c2 = *reinterpret_cast<const float4*>(&L->vvW2[4 * jq]);
            vv += fmaxf(V * c1.x + d1.x, 0.f) * c2.x;
            vv += fmaxf(V * c1.y + d1.y, 0.f) * c2.y;
            vv += fmaxf(V * c1.z + d1.z, 0.f) * c2.z;
            vv += fmaxf(V * c1.w + d1.w, 0.f) * c2.w;
        }
        vv = sp(vv);
        const float Vn = V + vd * h + vv * dB;

        const float drift   = rate - 0.5f * pd * pd;
        const float diff    = pd * dW;
        const float drift_c = 1.f + fabsf(drift) * sqh;
        const float diff_c  = 1.f + fabsf(pd) * sqh;
        const float Sln     = Slog + __fdividef(drift * h, drift_c) + __fdividef(diff, diff_c);
        const float Sn      = __expf(Sln);
        const float dS      = disc1 * Sn - disc0 * S;

        // ---- P5: control-variate accumulate + maturity pricing ------------
        if (m >= idx) {
#pragma unroll
            for (int si = 0; si < 6; si++)
                if (si < scnt) cv[si] += cvf[si] * dS;
        }
        if (im && m == idx) {
#pragma unroll
            for (int si = 0; si < 6; si++) {
                if (si < scnt) {
                    const float price = disc1 * fmaxf(Sn - Karr[si], 0.f) - cv[si];
                    float sm = price, sq = price * price;
                    for (int o = 32; o; o >>= 1) {
                        sm += __shfl_xor(sm, o);
                        sq += __shfl_xor(sq, o);
                    }
                    if (lane == 0) {
                        const int q = m * 21 + ss0 + si;
                        psum[q * NGROUP + blockIdx.x] = sm;
                        psq [q * NGROUP + blockIdx.x] = sq;
                    }
                }
            }
        }

        Slog = Sln; S = Sn; V = Vn;
    }
}

__global__ void lsv_finalize(const float* __restrict__ psum,
                             const float* __restrict__ psq,
                             float* __restrict__ out)
{
    const int t = blockIdx.x * blockDim.x + threadIdx.x;
    if (t >= NPAIR) return;
    float s = 0.f, q = 0.f;
    for (int b = 0; b < NGROUP; b++) {
        s += psum[t * NGROUP + b];
        q += psq [t * NGROUP + b];
    }
    const float mean = s * (1.0f / (float)MC);
    const float var  = (q - (float)MC * mean * mean) * (1.0f / (float)(MC - 1));
    out[t]         = mean;
    out[NPAIR + t] = var;
}

extern "C" void kernel_launch(void* const* d_in, const int* in_sizes, int n_in,
                              void* d_out, int out_size, void* d_ws, size_t ws_size,
                              hipStream_t stream)
{
    const float* S0    = (const float*)d_in[0];
    const float* rate  = (const float*)d_in[1];
    const float* z     = (const float*)d_in[2];
    const float* zz    = (const float*)d_in[3];
    const float* strikes = (const float*)d_in[5];
    const float* v0    = (const float*)d_in[6];
    const float* rho   = (const float*)d_in[7];
    const float* svW1  = (const float*)d_in[8];
    const float* svb1  = (const float*)d_in[9];
    const float* svW2  = (const float*)d_in[10];
    const float* svb2  = (const float*)d_in[11];
    const float* svW3  = (const float*)d_in[12];
    const float* svb3  = (const float*)d_in[13];
    const float* vhW1  = (const float*)d_in[14];
    const float* vhb1  = (const float*)d_in[15];
    const float* vhW2  = (const float*)d_in[16];
    const float* vhb2  = (const float*)d_in[17];
    const float* vdW1  = (const float*)d_in[18];
    const float* vdb1  = (const float*)d_in[19];
    const float* vdW2  = (const float*)d_in[20];
    const float* vdb2  = (const float*)d_in[21];
    const float* vvW1  = (const float*)d_in[22];
    const float* vvb1  = (const float*)d_in[23];
    const float* vvW2  = (const float*)d_in[24];
    const float* vvb2  = (const float*)d_in[25];
    const int*   mats  = (const int*)d_in[26];

    float* psum = (float*)d_ws;
    float* psq  = psum + NPAIR * NGROUP;

    hipLaunchKernelGGL(lsv_sim, dim3(NGROUP), dim3(BLOCK), 0, stream,
                       S0, rate, z, zz, strikes, v0, rho,
                       svW1, svb1, svW2, svb2, svW3, svb3,
                       vhW1, vhb1, vhW2, vhb2,
                       vdW1, vdb1, vdW2, vdb2,
                       vvW1, vvb1, vvW2, vvb2,
                       mats, psum, psq);

    hipLaunchKernelGGL(lsv_finalize, dim3(1), dim3(128), 0, stream,
                       psum, psq, (float*)d_out);
}

// Round 3
// 1583.776 us; speedup vs baseline: 4.0302x; 4.0302x over previous
//
#include <hip/hip_runtime.h>
#include <math.h>

// ---------------------------------------------------------------------------
// LSV Monte Carlo, round 3: the 64x100x100 per-block-step GEMM (s_vol layer 2)
// runs on MFMA (bf16 16x16x32). W2 staged once into LDS as bf16 B-fragments
// (stride 136 = bank-staggered, 16B aligned). h1 written as bf16 rows each
// step. Small nets (hedge / v-drift / v-vol) read weights from global with
// wave-uniform indices -> s_load through the scalar cache (R1-proven).
// __launch_bounds__(1024,4): VGPR cap 128 (fixes R2's scratch-spill disaster;
// grid = 256 blocks = exactly 1 block/CU, so higher residency is worthless).
// ---------------------------------------------------------------------------

#define MC      16384
#define NSTEP   96
#define NPATH   64
#define NWAVE   16
#define BLOCK   1024
#define NGROUP  256
#define NPAIR   84
#define KSTR    136            // LDS row stride (elements) for H1/Wb

typedef short bf16x8 __attribute__((ext_vector_type(8)));
typedef float f32x4  __attribute__((ext_vector_type(4)));

__device__ __forceinline__ unsigned int bf16rne(float x) {
    unsigned int u = __float_as_uint(x);
    return (u + 0x7FFFu + ((u >> 16) & 1u)) >> 16;
}
__device__ __forceinline__ float sp(float x) {   // softplus, fast
    return fmaxf(x, 0.f) + __logf(1.f + __expf(-fabsf(x)));
}

__global__ __launch_bounds__(BLOCK, 4)
void lsv_sim(const float* __restrict__ S0p,   const float* __restrict__ ratep,
             const float* __restrict__ z,     const float* __restrict__ zzg,
             const float* __restrict__ strikesg,
             const float* __restrict__ v0p,   const float* __restrict__ rhop,
             const float* __restrict__ svW1,  const float* __restrict__ svb1,
             const float* __restrict__ svW2,  const float* __restrict__ svb2,
             const float* __restrict__ svW3,  const float* __restrict__ svb3,
             const float* __restrict__ vhW1,  const float* __restrict__ vhb1,
             const float* __restrict__ vhW2,  const float* __restrict__ vhb2,
             const float* __restrict__ vdW1,  const float* __restrict__ vdb1,
             const float* __restrict__ vdW2,  const float* __restrict__ vdb2,
             const float* __restrict__ vvW1,  const float* __restrict__ vvb1,
             const float* __restrict__ vvW2,  const float* __restrict__ vvb2,
             const int*   __restrict__ mats,
             float* __restrict__ psum, float* __restrict__ psq)
{
    __shared__ unsigned short Wb[128 * KSTR];  // W2^T bf16, [j][k], zero-padded  34816 B
    __shared__ unsigned short H1[64 * KSTR];   // h1 bf16, [p][k], zero-padded    17408 B
    __shared__ float          RED[64 * 4];     // per-path partial pout by n-group 1024 B
    __shared__ float2         BW[128];         // {b2[j], W3[j]}, zero-padded      1024 B

    const int tid  = threadIdx.x;
    const int lane = tid & 63;
    const int w    = __builtin_amdgcn_readfirstlane(tid >> 6);
    const int col  = lane & 15;
    const int quad = lane >> 4;
    const int gpath = blockIdx.x * NPATH + lane;

    // ---- stage W2 as bf16 [j][k] (B^T layout), zero pad to 128x128 --------
    for (int e = tid; e < 128 * KSTR; e += BLOCK) {
        const int j = e / KSTR, kd = e - KSTR * j;
        const float v = (j < 100 && kd < 100) ? svW2[kd * 100 + j] : 0.f;
        Wb[e] = (unsigned short)bf16rne(v);
    }
    for (int e = tid; e < 128; e += BLOCK)
        BW[e] = make_float2(e < 100 ? svb2[e] : 0.f, e < 100 ? svW3[e] : 0.f);

    // ---- uniform setup -----------------------------------------------------
    const float rate  = ratep[0];
    const float S0    = S0p[0];
    const float rho_t = tanhf(rhop[0]);
    const float srho  = sqrtf(1.f - rho_t * rho_t);
    const float b3    = svb3[0];
    const float vdb2s = vdb2[0];
    const float vvb2s = vvb2[0];
    int matr[4];
#pragma unroll
    for (int k = 0; k < 4; k++) matr[k] = mats[k];

    // GEMM roles: wave w -> m-tile (paths), n-pair (j columns)
    const int m0 = 16 * (w & 3);
    const int ng = w >> 2;                 // n-group 0..3
    const int n0 = 32 * ng;
    const int aoff  = (m0 + col) * KSTR + 8 * quad;          // shorts
    const int b0off = (n0 + col) * KSTR + 8 * quad;
    const int b1off = b0off + 16 * KSTR;

    // hedge roles: wave w -> maturity hm, strike slice
    const int hm   = w >> 2;
    const int q4   = w & 3;
    const int ss0  = (q4 == 0) ? 0 : (6 + 5 * (q4 - 1));
    const int scnt = (q4 == 0) ? 6 : 5;

    // P1 roles: thread -> (path pp, k-chunk kc of 8)
    const int pp = tid >> 4;
    const int kc = tid & 15;

    // ---- per-path state (lane = path, redundant across waves) -------------
    float Slog = __logf(S0);
    float S    = __expf(Slog);
    float V    = (1.f / (1.f + __expf(-v0p[0]))) * 0.5f;
    float cv[6];
#pragma unroll
    for (int si = 0; si < 6; si++) cv[si] = 0.f;

    const float* zrow  = z   + (size_t)gpath * NSTEP;
    const float* zzrow = zzg + (size_t)gpath * NSTEP;

    __syncthreads();   // Wb/BW staged

    for (int i = 0; i < NSTEP; i++) {
        const float zi  = zrow[i];
        const float zzi = zzrow[i];

        const float t0    = (float)i       / 365.0f;
        const float t1    = (float)(i + 1) / 365.0f;
        const float h     = t1 - t0;
        const float sqh   = sqrtf(h);
        const float disc0 = __expf(-rate * t0);
        const float disc1 = __expf(-rate * t1);
        const int   day   = i + 1;
        int idx = 0;
        while (idx < 3 && day > matr[idx]) idx++;
        const bool im = (day == matr[idx]);

        // ---- P1: h1 row-chunk (8 k's for path pp) -> bf16 in LDS ----------
        {
            const float sl_p = __shfl(Slog, pp);
            const float v_p  = __shfl(V, pp);
            float hv[8];
#pragma unroll
            for (int e = 0; e < 8; e++) {
                const int kk = 8 * kc + e;
                const int sk = (kk < 100) ? kk : 0;       // safe index
                const float x = t0 * svW1[sk] + sl_p * svW1[100 + sk]
                              + v_p * svW1[200 + sk] + svb1[sk];
                hv[e] = (kk < 100) ? fmaxf(x, 0.f) : 0.f;
            }
            uint4 pk;
            pk.x = bf16rne(hv[0]) | (bf16rne(hv[1]) << 16);
            pk.y = bf16rne(hv[2]) | (bf16rne(hv[3]) << 16);
            pk.z = bf16rne(hv[4]) | (bf16rne(hv[5]) << 16);
            pk.w = bf16rne(hv[6]) | (bf16rne(hv[7]) << 16);
            *reinterpret_cast<uint4*>(H1 + pp * KSTR + kc * 8) = pk;
        }
        __syncthreads();

        // ---- P2: MFMA GEMM S[64p][128j] = h1[64][128k] * W2[128k][128j] ----
        f32x4 d0 = {0.f, 0.f, 0.f, 0.f};
        f32x4 d1 = {0.f, 0.f, 0.f, 0.f};
#pragma unroll
        for (int c = 0; c < 4; c++) {
            const bf16x8 a  = *reinterpret_cast<const bf16x8*>(H1 + aoff  + 32 * c);
            const bf16x8 b0 = *reinterpret_cast<const bf16x8*>(Wb + b0off + 32 * c);
            const bf16x8 b1 = *reinterpret_cast<const bf16x8*>(Wb + b1off + 32 * c);
            d0 = __builtin_amdgcn_mfma_f32_16x16x32_bf16(a, b0, d0, 0, 0, 0);
            d1 = __builtin_amdgcn_mfma_f32_16x16x32_bf16(a, b1, d1, 0, 0, 0);
        }
        // relu(S+b2)*W3, reduce over this wave's 32 j-cols per path-row
        {
            const float2 bw0 = BW[n0 + col];
            const float2 bw1 = BW[n0 + 16 + col];
            float sr[4];
#pragma unroll
            for (int r = 0; r < 4; r++)
                sr[r] = fmaxf(d0[r] + bw0.x, 0.f) * bw0.y
                      + fmaxf(d1[r] + bw1.x, 0.f) * bw1.y;
#pragma unroll
            for (int msk = 1; msk <= 8; msk <<= 1) {
                sr[0] += __shfl_xor(sr[0], msk);
                sr[1] += __shfl_xor(sr[1], msk);
                sr[2] += __shfl_xor(sr[2], msk);
                sr[3] += __shfl_xor(sr[3], msk);
            }
            const float outv = (col == 0) ? sr[0] : (col == 1) ? sr[1]
                             : (col == 2) ? sr[2] : sr[3];
            if (col < 4)
                RED[(m0 + 4 * quad + col) * 4 + ng] = outv;
        }

        // ---- P3: vanilla hedge (m=hm, strike slice), weights via s_load ----
        float h1vh[20];
#pragma unroll
        for (int j = 0; j < 20; j++)
            h1vh[j] = fmaxf(t0 * vhW1[hm * 40 + j] + Slog * vhW1[hm * 40 + 20 + j]
                            + vhb1[hm * 20 + j], 0.f);
        float cvf[6];
#pragma unroll
        for (int si = 0; si < 6; si++) {
            if (si < scnt) {
                const int s = ss0 + si;
                float a = vhb2[hm * 21 + s];
#pragma unroll
                for (int j = 0; j < 20; j++)
                    a += h1vh[j] * vhW2[hm * 420 + j * 21 + s];
                cvf[si] = sp(a);
            } else cvf[si] = 0.f;
        }
        __syncthreads();

        // ---- P4: finish step (redundant per wave; state stays in regs) -----
        const float4 rr = *reinterpret_cast<const float4*>(RED + lane * 4);
        const float pout = (rr.x + rr.y) + (rr.z + rr.w);
        const float pd = sp(pout + b3);

        const float dW = sqh * zi;
        const float dB = rho_t * dW + srho * sqh * zzi;

        float vd = vdb2s, vv = vvb2s;
#pragma unroll
        for (int j = 0; j < 20; j++) {
            vd += fmaxf(V * vdW1[j] + vdb1[j], 0.f) * vdW2[j];
            vv += fmaxf(V * vvW1[j] + vvb1[j], 0.f) * vvW2[j];
        }
        vv = sp(vv);
        const float Vn = V + vd * h + vv * dB;

        const float drift   = rate - 0.5f * pd * pd;
        const float diff    = pd * dW;
        const float drift_c = 1.f + fabsf(drift) * sqh;
        const float diff_c  = 1.f + fabsf(pd) * sqh;
        const float Sln     = Slog + __fdividef(drift * h, drift_c)
                                   + __fdividef(diff, diff_c);
        const float Sn      = __expf(Sln);
        const float dS      = disc1 * Sn - disc0 * S;

        // ---- P5: control-variate accumulate + maturity pricing -------------
        if (hm >= idx) {
#pragma unroll
            for (int si = 0; si < 6; si++)
                if (si < scnt) cv[si] += cvf[si] * dS;
        }
        if (im && hm == idx) {
#pragma unroll
            for (int si = 0; si < 6; si++) {
                if (si < scnt) {
                    const int s = ss0 + si;
                    const float K = strikesg[s];
                    const float price = disc1 * fmaxf(Sn - K, 0.f) - cv[si];
                    float sm = price, sq = price * price;
                    for (int o = 32; o; o >>= 1) {
                        sm += __shfl_xor(sm, o);
                        sq += __shfl_xor(sq, o);
                    }
                    if (lane == 0) {
                        const int q = hm * 21 + s;
                        psum[q * NGROUP + blockIdx.x] = sm;
                        psq [q * NGROUP + blockIdx.x] = sq;
                    }
                }
            }
        }

        Slog = Sln; S = Sn; V = Vn;
    }
}

__global__ void lsv_finalize(const float* __restrict__ psum,
                             const float* __restrict__ psq,
                             float* __restrict__ out)
{
    const int t = blockIdx.x * blockDim.x + threadIdx.x;
    if (t >= NPAIR) return;
    float s = 0.f, q = 0.f;
    for (int b = 0; b < NGROUP; b++) {
        s += psum[t * NGROUP + b];
        q += psq [t * NGROUP + b];
    }
    const float mean = s * (1.0f / (float)MC);
    const float var  = (q - (float)MC * mean * mean) * (1.0f / (float)(MC - 1));
    out[t]         = mean;
    out[NPAIR + t] = var;
}

extern "C" void kernel_launch(void* const* d_in, const int* in_sizes, int n_in,
                              void* d_out, int out_size, void* d_ws, size_t ws_size,
                              hipStream_t stream)
{
    const float* S0    = (const float*)d_in[0];
    const float* rate  = (const float*)d_in[1];
    const float* z     = (const float*)d_in[2];
    const float* zz    = (const float*)d_in[3];
    const float* strikes = (const float*)d_in[5];
    const float* v0    = (const float*)d_in[6];
    const float* rho   = (const float*)d_in[7];
    const float* svW1  = (const float*)d_in[8];
    const float* svb1  = (const float*)d_in[9];
    const float* svW2  = (const float*)d_in[10];
    const float* svb2  = (const float*)d_in[11];
    const float* svW3  = (const float*)d_in[12];
    const float* svb3  = (const float*)d_in[13];
    const float* vhW1  = (const float*)d_in[14];
    const float* vhb1  = (const float*)d_in[15];
    const float* vhW2  = (const float*)d_in[16];
    const float* vhb2  = (const float*)d_in[17];
    const float* vdW1  = (const float*)d_in[18];
    const float* vdb1  = (const float*)d_in[19];
    const float* vdW2  = (const float*)d_in[20];
    const float* vdb2  = (const float*)d_in[21];
    const float* vvW1  = (const float*)d_in[22];
    const float* vvb1  = (const float*)d_in[23];
    const float* vvW2  = (const float*)d_in[24];
    const float* vvb2  = (const float*)d_in[25];
    const int*   mats  = (const int*)d_in[26];

    float* psum = (float*)d_ws;
    float* psq  = psum + NPAIR * NGROUP;

    hipLaunchKernelGGL(lsv_sim, dim3(NGROUP), dim3(BLOCK), 0, stream,
                       S0, rate, z, zz, strikes, v0, rho,
                       svW1, svb1, svW2, svb2, svW3, svb3,
                       vhW1, vhb1, vhW2, vhb2,
                       vdW1, vdb1, vdW2, vdb2,
                       vvW1, vvb1, vvW2, vvb2,
                       mats, psum, psq);

    hipLaunchKernelGGL(lsv_finalize, dim3(1), dim3(128), 0, stream,
                       psum, psq, (float*)d_out);
}

// Round 4
// 1250.774 us; speedup vs baseline: 5.1031x; 1.2662x over previous
//
#include <hip/hip_runtime.h>
#include <math.h>

// ---------------------------------------------------------------------------
// LSV Monte Carlo, round 4.
// Key idea: ALL loop-invariant weights live in VGPRs (bf16-packed) or a tiny
// LDS table -- zero per-step global loads except z/zz. Both the s_vol 100x100
// layer AND the hedge layer-2 run on MFMA (bf16 16x16x32). Hedge is processed
// one step LAGGED so it overlaps the critical path. vd/vv nets computed once
// by waves 14/15 (not 16x redundantly) and broadcast via LDS double-buffer.
// 256 blocks x 1024 threads, lane = path.
// ---------------------------------------------------------------------------

#define MC      16384
#define NSTEP   96
#define NWAVE   16
#define BLOCK   1024
#define NGROUP  256
#define NPAIR   84
#define KSTR    136            // H1 row stride in shorts (16B-aligned, staggered)

typedef short bf16x8 __attribute__((ext_vector_type(8)));
typedef float f32x4  __attribute__((ext_vector_type(4)));

union U8 { uint4 u; bf16x8 v; };

__device__ __forceinline__ unsigned bf16rne(float x) {
    unsigned u = __float_as_uint(x);
    return (u + 0x7FFFu + ((u >> 16) & 1u)) >> 16;
}
__device__ __forceinline__ float blo(unsigned p) { return __uint_as_float(p << 16); }
__device__ __forceinline__ float bhi(unsigned p) { return __uint_as_float(p & 0xFFFF0000u); }
__device__ __forceinline__ float sp(float x) {   // softplus
    return fmaxf(x, 0.f) + __logf(1.f + __expf(-fabsf(x)));
}

__global__ __launch_bounds__(BLOCK, 4)
void lsv_sim(const float* __restrict__ S0p,   const float* __restrict__ ratep,
             const float* __restrict__ z,     const float* __restrict__ zzg,
             const float* __restrict__ strikesg,
             const float* __restrict__ v0p,   const float* __restrict__ rhop,
             const float* __restrict__ svW1,  const float* __restrict__ svb1,
             const float* __restrict__ svW2,  const float* __restrict__ svb2,
             const float* __restrict__ svW3,  const float* __restrict__ svb3,
             const float* __restrict__ vhW1,  const float* __restrict__ vhb1,
             const float* __restrict__ vhW2,  const float* __restrict__ vhb2,
             const float* __restrict__ vdW1,  const float* __restrict__ vdb1,
             const float* __restrict__ vdW2,  const float* __restrict__ vdb2,
             const float* __restrict__ vvW1,  const float* __restrict__ vvb1,
             const float* __restrict__ vvW2,  const float* __restrict__ vvb2,
             const int*   __restrict__ mats,
             float* __restrict__ psum, float* __restrict__ psq)
{
    __shared__ unsigned short H1[64 * KSTR];       // 17408 B  h1 bf16 [p][k]
    __shared__ float RED[64 * 4];                  // 1024 B   per-path pout partials
    __shared__ float VDl[2][64], VVl[2][64];       // 1024 B   v-drift/v-vol broadcast
    __shared__ float PSs[4][32], PSq[4][32];       // 1024 B   maturity partials
    __shared__ float VW[128];                      // 512 B    vd/vv weight table

    const int tid  = threadIdx.x;
    const int lane = tid & 63;
    const int w    = __builtin_amdgcn_readfirstlane(tid >> 6);
    const int quad = lane >> 4;
    const int col  = lane & 15;
    const int gpath = blockIdx.x * 64 + lane;

    // ---- stage vd/vv weight table ------------------------------------------
    for (int e = tid; e < 128; e += BLOCK) {
        float v = 0.f;
        if      (e < 20)             v = vdW1[e];
        else if (e < 40)             v = vdb1[e - 20];
        else if (e < 60)             v = vdW2[e - 40];
        else if (e >= 64 && e < 84)  v = vvW1[e - 64];
        else if (e >= 84 && e < 104) v = vvb1[e - 84];
        else if (e >= 104 && e < 124)v = vvW2[e - 104];
        VW[e] = v;
    }

    // ---- uniform setup -----------------------------------------------------
    const float rate  = ratep[0];
    const float S0    = S0p[0];
    const float rho_t = tanhf(rhop[0]);
    const float srho  = sqrtf(1.f - rho_t * rho_t);
    const float b3    = svb3[0];
    const float vdb2s = vdb2[0];
    const float vvb2s = vvb2[0];
    int matr[4];
#pragma unroll
    for (int k = 0; k < 4; k++) matr[k] = mats[k];

    // GEMM roles (main): m-tile m0, n-group ng
    const int m0 = 16 * (w & 3);
    const int ng = w >> 2;
    // hedge roles: maturity m, path-tile pt
    const int m  = w >> 2;
    const int pt = w & 3;

    // ---- preload invariant weights into VGPRs ------------------------------
    // main-GEMM B fragments: Bf[c][st], k = 32c+8*quad+e, j = 32*ng+16*st+col
    bf16x8 Bf[4][2];
#pragma unroll
    for (int c = 0; c < 4; c++)
#pragma unroll
        for (int st = 0; st < 2; st++) {
            U8 t;
#pragma unroll
            for (int e2 = 0; e2 < 4; e2++) {
                const int k0 = 32 * c + 8 * quad + 2 * e2;
                const int j  = 32 * ng + 16 * st + col;
                const float v0 = (k0     < 100 && j < 100) ? svW2[k0 * 100 + j]       : 0.f;
                const float v1 = (k0 + 1 < 100 && j < 100) ? svW2[(k0 + 1) * 100 + j] : 0.f;
                (&t.u.x)[e2] = bf16rne(v0) | (bf16rne(v1) << 16);
            }
            Bf[c][st] = t.v;
        }
    // main epilogue consts: {b2[j], W3[j]} for this lane's two j's
    const int jA = 32 * ng + col, jB = jA + 16;
    const float2 bw0 = make_float2(jA < 100 ? svb2[jA] : 0.f, jA < 100 ? svW3[jA] : 0.f);
    const float2 bw1 = make_float2(jB < 100 ? svb2[jB] : 0.f, jB < 100 ? svW3[jB] : 0.f);

    // P1 weight slice (svW1 rows + bias) for k = 8*col + e, bf16-packed
    unsigned wa[4], wb[4], wc[4], wd[4];
#pragma unroll
    for (int e2 = 0; e2 < 4; e2++) {
        const int k0 = 8 * col + 2 * e2, k1 = k0 + 1;
        const float a0 = k0 < 100 ? svW1[k0] : 0.f,        a1 = k1 < 100 ? svW1[k1] : 0.f;
        const float b0 = k0 < 100 ? svW1[100 + k0] : 0.f,  b1 = k1 < 100 ? svW1[100 + k1] : 0.f;
        const float c0 = k0 < 100 ? svW1[200 + k0] : 0.f,  c1 = k1 < 100 ? svW1[200 + k1] : 0.f;
        const float d0 = k0 < 100 ? svb1[k0] : 0.f,        d1 = k1 < 100 ? svb1[k1] : 0.f;
        wa[e2] = bf16rne(a0) | (bf16rne(a1) << 16);
        wb[e2] = bf16rne(b0) | (bf16rne(b1) << 16);
        wc[e2] = bf16rne(c0) | (bf16rne(c1) << 16);
        wd[e2] = bf16rne(d0) | (bf16rne(d1) << 16);
    }

    // hedge layer-1 slice for j = 8*quad + e (maturity m), bf16-packed
    unsigned wtp[4], wsp[4], bbp[4];
#pragma unroll
    for (int e2 = 0; e2 < 4; e2++) {
        const int j0 = 8 * quad + 2 * e2, j1 = j0 + 1;
        const float t0v = j0 < 20 ? vhW1[m * 40 + j0] : 0.f;
        const float t1v = j1 < 20 ? vhW1[m * 40 + j1] : 0.f;
        const float s0v = j0 < 20 ? vhW1[m * 40 + 20 + j0] : 0.f;
        const float s1v = j1 < 20 ? vhW1[m * 40 + 20 + j1] : 0.f;
        const float b0v = j0 < 20 ? vhb1[m * 20 + j0] : 0.f;
        const float b1v = j1 < 20 ? vhb1[m * 20 + j1] : 0.f;
        wtp[e2] = bf16rne(t0v) | (bf16rne(t1v) << 16);
        wsp[e2] = bf16rne(s0v) | (bf16rne(s1v) << 16);
        bbp[e2] = bf16rne(b0v) | (bf16rne(b1v) << 16);
    }
    // hedge layer-2 B fragments: Bh[st], k = 8*quad+e (j), s = 16*st+col
    bf16x8 Bh[2];
#pragma unroll
    for (int st = 0; st < 2; st++) {
        U8 t;
#pragma unroll
        for (int e2 = 0; e2 < 4; e2++) {
            const int k0 = 8 * quad + 2 * e2, k1 = k0 + 1;
            const int s  = 16 * st + col;
            const float v0 = (k0 < 20 && s < 21) ? vhW2[m * 420 + k0 * 21 + s] : 0.f;
            const float v1 = (k1 < 20 && s < 21) ? vhW2[m * 420 + k1 * 21 + s] : 0.f;
            (&t.u.x)[e2] = bf16rne(v0) | (bf16rne(v1) << 16);
        }
        Bh[st] = t.v;
    }
    const int sA = col, sB = 16 + col;
    const float b2s0 = vhb2[m * 21 + sA];                       // col<16 always valid? col<=15<21 yes
    const float b2s1 = (sB < 21) ? vhb2[m * 21 + sB] : 0.f;
    const float K0   = strikesg[sA];
    const float K1   = (sB < 21) ? strikesg[sB] : 1e30f;

    // ---- per-path state ----------------------------------------------------
    float Slog = __logf(S0);
    float S    = __expf(Slog);
    float V    = (1.f / (1.f + __expf(-v0p[0]))) * 0.5f;
    f32x4 cv0 = {0.f, 0.f, 0.f, 0.f};
    f32x4 cv1 = {0.f, 0.f, 0.f, 0.f};
    float Slog_prev = 0.f, dS_prev = 0.f, disc1_prev = 1.f, t0_prev = 0.f;
    int   idx_prev = 0;
    bool  im_prev  = false;

    const float* zrow  = z   + (size_t)gpath * NSTEP;
    const float* zzrow = zzg + (size_t)gpath * NSTEP;

    const int pp = 4 * w + quad;             // P1: path this thread computes h1 for
    const int pbase = 16 * pt + 4 * quad;    // hedge: first path of my C-rows

    __syncthreads();   // VW staged

    // ---- lagged hedge step (uses *_prev state) -----------------------------
    auto hedge_step = [&]() {
        if (m >= idx_prev) {
            const float slp = __shfl(Slog_prev, 16 * pt + col);
            U8 a;
#pragma unroll
            for (int e2 = 0; e2 < 4; e2++) {
                const float h0 = fmaxf(t0_prev * blo(wtp[e2]) + slp * blo(wsp[e2]) + blo(bbp[e2]), 0.f);
                const float h1 = fmaxf(t0_prev * bhi(wtp[e2]) + slp * bhi(wsp[e2]) + bhi(bbp[e2]), 0.f);
                (&a.u.x)[e2] = bf16rne(h0) | (bf16rne(h1) << 16);
            }
            const f32x4 z4 = {0.f, 0.f, 0.f, 0.f};
            const f32x4 D0 = __builtin_amdgcn_mfma_f32_16x16x32_bf16(a.v, Bh[0], z4, 0, 0, 0);
            const f32x4 D1 = __builtin_amdgcn_mfma_f32_16x16x32_bf16(a.v, Bh[1], z4, 0, 0, 0);
            float dsr[4];
#pragma unroll
            for (int r = 0; r < 4; r++) dsr[r] = __shfl(dS_prev, pbase + r);
#pragma unroll
            for (int r = 0; r < 4; r++) {
                cv0[r] += sp(D0[r] + b2s0) * dsr[r];
                cv1[r] += sp(D1[r] + b2s1) * dsr[r];
            }
            if (im_prev && m == idx_prev) {
                float s0 = 0.f, q0 = 0.f, s1 = 0.f, q1 = 0.f;
#pragma unroll
                for (int r = 0; r < 4; r++) {
                    const float Sp = __shfl(S, pbase + r);
                    const float p0 = disc1_prev * fmaxf(Sp - K0, 0.f) - cv0[r];
                    const float p1 = disc1_prev * fmaxf(Sp - K1, 0.f) - cv1[r];
                    s0 += p0; q0 += p0 * p0;
                    s1 += p1; q1 += p1 * p1;
                }
                s0 += __shfl_xor(s0, 16); s0 += __shfl_xor(s0, 32);
                q0 += __shfl_xor(q0, 16); q0 += __shfl_xor(q0, 32);
                s1 += __shfl_xor(s1, 16); s1 += __shfl_xor(s1, 32);
                q1 += __shfl_xor(q1, 16); q1 += __shfl_xor(q1, 32);
                if (quad == 0) {
                    PSs[pt][col] = s0;  PSq[pt][col] = q0;
                    if (col < 5) { PSs[pt][16 + col] = s1;  PSq[pt][16 + col] = q1; }
                }
            }
        }
    };

    auto ps_reduce = [&]() {
        if (w == 0 && im_prev) {
            const int s = lane & 31;
            if (s < 21) {
                const float* src = (lane >= 32) ? &PSq[0][0] : &PSs[0][0];
                const float acc = src[s] + src[32 + s] + src[64 + s] + src[96 + s];
                float* dst = (lane >= 32) ? psq : psum;
                dst[(idx_prev * 21 + s) * NGROUP + blockIdx.x] = acc;
            }
        }
    };

    for (int i = 0; i < NSTEP; i++) {
        const float zi  = zrow[i];
        const float zzi = zzrow[i];

        const float t0    = (float)i       * (1.f / 365.f);
        const float t1    = (float)(i + 1) * (1.f / 365.f);
        const float h     = t1 - t0;
        const float sqh   = sqrtf(h);
        const float disc0 = __expf(-rate * t0);
        const float disc1 = __expf(-rate * t1);
        const int   day   = i + 1;
        const int   idx   = (day > matr[0]) + (day > matr[1]) + (day > matr[2]);
        const bool  im    = (day == matr[idx]);

        // ===== Region 1: P1 h1-write | lagged hedge | vd/vv nets ============
        {
            const float slp = __shfl(Slog, pp);
            const float vp  = __shfl(V, pp);
            uint4 o;
#pragma unroll
            for (int e2 = 0; e2 < 4; e2++) {
                const float h0 = fmaxf(t0 * blo(wa[e2]) + slp * blo(wb[e2]) + vp * blo(wc[e2]) + blo(wd[e2]), 0.f);
                const float h1 = fmaxf(t0 * bhi(wa[e2]) + slp * bhi(wb[e2]) + vp * bhi(wc[e2]) + bhi(wd[e2]), 0.f);
                (&o.x)[e2] = bf16rne(h0) | (bf16rne(h1) << 16);
            }
            *reinterpret_cast<uint4*>(H1 + pp * KSTR + col * 8) = o;
        }
        if (i > 0) hedge_step();
        if (w == 14) {                      // v-drift net for all 64 paths
            float acc = vdb2s;
#pragma unroll
            for (int q5 = 0; q5 < 5; q5++) {
                const float4 w1 = *reinterpret_cast<const float4*>(VW + 4 * q5);
                const float4 b1 = *reinterpret_cast<const float4*>(VW + 20 + 4 * q5);
                const float4 w2 = *reinterpret_cast<const float4*>(VW + 40 + 4 * q5);
                acc += fmaxf(V * w1.x + b1.x, 0.f) * w2.x;
                acc += fmaxf(V * w1.y + b1.y, 0.f) * w2.y;
                acc += fmaxf(V * w1.z + b1.z, 0.f) * w2.z;
                acc += fmaxf(V * w1.w + b1.w, 0.f) * w2.w;
            }
            VDl[i & 1][lane] = acc;
        }
        if (w == 15) {                      // v-vol net for all 64 paths
            float acc = vvb2s;
#pragma unroll
            for (int q5 = 0; q5 < 5; q5++) {
                const float4 w1 = *reinterpret_cast<const float4*>(VW + 64 + 4 * q5);
                const float4 b1 = *reinterpret_cast<const float4*>(VW + 84 + 4 * q5);
                const float4 w2 = *reinterpret_cast<const float4*>(VW + 104 + 4 * q5);
                acc += fmaxf(V * w1.x + b1.x, 0.f) * w2.x;
                acc += fmaxf(V * w1.y + b1.y, 0.f) * w2.y;
                acc += fmaxf(V * w1.z + b1.z, 0.f) * w2.z;
                acc += fmaxf(V * w1.w + b1.w, 0.f) * w2.w;
            }
            VVl[i & 1][lane] = sp(acc);
        }
        __syncthreads();

        // ===== Region 2: main MFMA GEMM + reduce | PS global write ==========
        {
            f32x4 d0 = {0.f, 0.f, 0.f, 0.f};
            f32x4 d1 = {0.f, 0.f, 0.f, 0.f};
#pragma unroll
            for (int c = 0; c < 4; c++) {
                const bf16x8 afr = *reinterpret_cast<const bf16x8*>(H1 + (m0 + col) * KSTR + 8 * quad + 32 * c);
                d0 = __builtin_amdgcn_mfma_f32_16x16x32_bf16(afr, Bf[c][0], d0, 0, 0, 0);
                d1 = __builtin_amdgcn_mfma_f32_16x16x32_bf16(afr, Bf[c][1], d1, 0, 0, 0);
            }
            float sr[4];
#pragma unroll
            for (int r = 0; r < 4; r++)
                sr[r] = fmaxf(d0[r] + bw0.x, 0.f) * bw0.y + fmaxf(d1[r] + bw1.x, 0.f) * bw1.y;
#pragma unroll
            for (int msk = 1; msk <= 8; msk <<= 1) {
                sr[0] += __shfl_xor(sr[0], msk);
                sr[1] += __shfl_xor(sr[1], msk);
                sr[2] += __shfl_xor(sr[2], msk);
                sr[3] += __shfl_xor(sr[3], msk);
            }
            const float outv = (col == 0) ? sr[0] : (col == 1) ? sr[1]
                             : (col == 2) ? sr[2] : sr[3];
            if (col < 4)
                RED[(m0 + 4 * quad + col) * 4 + ng] = outv;
        }
        ps_reduce();
        __syncthreads();

        // ===== Region 3: SDE tail (redundant per wave, state in regs) =======
        {
            const float4 rr = *reinterpret_cast<const float4*>(RED + lane * 4);
            const float pout = (rr.x + rr.y) + (rr.z + rr.w);
            const float pd = sp(pout + b3);
            const float vdv = VDl[i & 1][lane];
            const float vvv = VVl[i & 1][lane];
            const float dW = sqh * zi;
            const float dB = rho_t * dW + srho * sqh * zzi;
            const float Vn = V + vdv * h + vvv * dB;
            const float drift   = rate - 0.5f * pd * pd;
            const float diff    = pd * dW;
            const float drift_c = 1.f + fabsf(drift) * sqh;
            const float diff_c  = 1.f + fabsf(pd) * sqh;
            const float Sln = Slog + __fdividef(drift * h, drift_c) + __fdividef(diff, diff_c);
            const float Sn  = __expf(Sln);
            const float dS  = disc1 * Sn - disc0 * S;
            Slog_prev = Slog; dS_prev = dS; disc1_prev = disc1; t0_prev = t0;
            idx_prev = idx; im_prev = im;
            Slog = Sln; S = Sn; V = Vn;
        }
    }

    // ---- epilogue: process step 95's hedge + final maturity flush ----------
    hedge_step();
    __syncthreads();
    ps_reduce();
}

__global__ void lsv_finalize(const float* __restrict__ psum,
                             const float* __restrict__ psq,
                             float* __restrict__ out)
{
    const int t = blockIdx.x * blockDim.x + threadIdx.x;
    if (t >= NPAIR) return;
    float s = 0.f, q = 0.f;
    for (int b = 0; b < NGROUP; b++) {
        s += psum[t * NGROUP + b];
        q += psq [t * NGROUP + b];
    }
    const float mean = s * (1.0f / (float)MC);
    const float var  = (q - (float)MC * mean * mean) * (1.0f / (float)(MC - 1));
    out[t]         = mean;
    out[NPAIR + t] = var;
}

extern "C" void kernel_launch(void* const* d_in, const int* in_sizes, int n_in,
                              void* d_out, int out_size, void* d_ws, size_t ws_size,
                              hipStream_t stream)
{
    const float* S0    = (const float*)d_in[0];
    const float* rate  = (const float*)d_in[1];
    const float* z     = (const float*)d_in[2];
    const float* zz    = (const float*)d_in[3];
    const float* strikes = (const float*)d_in[5];
    const float* v0    = (const float*)d_in[6];
    const float* rho   = (const float*)d_in[7];
    const float* svW1  = (const float*)d_in[8];
    const float* svb1  = (const float*)d_in[9];
    const float* svW2  = (const float*)d_in[10];
    const float* svb2  = (const float*)d_in[11];
    const float* svW3  = (const float*)d_in[12];
    const float* svb3  = (const float*)d_in[13];
    const float* vhW1  = (const float*)d_in[14];
    const float* vhb1  = (const float*)d_in[15];
    const float* vhW2  = (const float*)d_in[16];
    const float* vhb2  = (const float*)d_in[17];
    const float* vdW1  = (const float*)d_in[18];
    const float* vdb1  = (const float*)d_in[19];
    const float* vdW2  = (const float*)d_in[20];
    const float* vdb2  = (const float*)d_in[21];
    const float* vvW1  = (const float*)d_in[22];
    const float* vvb1  = (const float*)d_in[23];
    const float* vvW2  = (const float*)d_in[24];
    const float* vvb2  = (const float*)d_in[25];
    const int*   mats  = (const int*)d_in[26];

    float* psum = (float*)d_ws;
    float* psq  = psum + NPAIR * NGROUP;

    hipLaunchKernelGGL(lsv_sim, dim3(NGROUP), dim3(BLOCK), 0, stream,
                       S0, rate, z, zz, strikes, v0, rho,
                       svW1, svb1, svW2, svb2, svW3, svb3,
                       vhW1, vhb1, vhW2, vhb2,
                       vdW1, vdb1, vdW2, vdb2,
                       vvW1, vvb1, vvW2, vvb2,
                       mats, psum, psq);

    hipLaunchKernelGGL(lsv_finalize, dim3(1), dim3(128), 0, stream,
                       psum, psq, (float*)d_out);
}

// Round 5
// 516.336 us; speedup vs baseline: 12.3619x; 2.4224x over previous
//
#include <hip/hip_runtime.h>
#include <math.h>

// ---------------------------------------------------------------------------
// LSV Monte Carlo, round 5.
// R4 post-mortem: per-thread invariant preload (~140 regs) exceeded the
// 128-VGPR cap of a 16-wave block -> scratch spill (91 MB WS, 1.7 GB/step
// reload = the whole runtime). Fix: only MFMA B-fragments stay in registers
// (compiler parks them in AGPRs, read directly by MFMA); VALU-consumed packed
// weights move to small LDS broadcast tables (W1T 1KB, WH1 768B) re-read per
// step with ds_read_b128 (16/4 distinct addresses -> HW broadcast).
// ---------------------------------------------------------------------------

#define MC      16384
#define NSTEP   96
#define NWAVE   16
#define BLOCK   1024
#define NGROUP  256
#define NPAIR   84
#define KSTR    136            // H1 row stride in shorts

typedef short bf16x8 __attribute__((ext_vector_type(8)));
typedef float f32x4  __attribute__((ext_vector_type(4)));

union U8 { uint4 u; bf16x8 v; };

__device__ __forceinline__ unsigned bf16rne(float x) {
    unsigned u = __float_as_uint(x);
    return (u + 0x7FFFu + ((u >> 16) & 1u)) >> 16;
}
__device__ __forceinline__ float blo(unsigned p) { return __uint_as_float(p << 16); }
__device__ __forceinline__ float bhi(unsigned p) { return __uint_as_float(p & 0xFFFF0000u); }
__device__ __forceinline__ float sp(float x) {
    return fmaxf(x, 0.f) + __logf(1.f + __expf(-fabsf(x)));
}

__global__ __launch_bounds__(BLOCK, 4)
void lsv_sim(const float* __restrict__ S0p,   const float* __restrict__ ratep,
             const float* __restrict__ z,     const float* __restrict__ zzg,
             const float* __restrict__ strikesg,
             const float* __restrict__ v0p,   const float* __restrict__ rhop,
             const float* __restrict__ svW1,  const float* __restrict__ svb1,
             const float* __restrict__ svW2,  const float* __restrict__ svb2,
             const float* __restrict__ svW3,  const float* __restrict__ svb3,
             const float* __restrict__ vhW1,  const float* __restrict__ vhb1,
             const float* __restrict__ vhW2,  const float* __restrict__ vhb2,
             const float* __restrict__ vdW1,  const float* __restrict__ vdb1,
             const float* __restrict__ vdW2,  const float* __restrict__ vdb2,
             const float* __restrict__ vvW1,  const float* __restrict__ vvb1,
             const float* __restrict__ vvW2,  const float* __restrict__ vvb2,
             const int*   __restrict__ mats,
             float* __restrict__ psum, float* __restrict__ psq)
{
    __shared__ unsigned short H1[64 * KSTR];
    __shared__ float RED[64 * 4];
    __shared__ float VDl[2][64], VVl[2][64];
    __shared__ float PSs[4][32], PSq[4][32];
    __shared__ float VW[128];
    __shared__ uint4 W1T[16][4];
    __shared__ uint4 WH1[4][4][3];

    const int tid  = threadIdx.x;
    const int lane = tid & 63;
    const int w    = __builtin_amdgcn_readfirstlane(tid >> 6);
    const int quad = lane >> 4;
    const int col  = lane & 15;
    const int gpath = blockIdx.x * 64 + lane;

    // ---- stage vd/vv weight table (124/125 hold the layer-2 biases) --------
    for (int e = tid; e < 128; e += BLOCK) {
        float v = 0.f;
        if      (e < 20)             v = vdW1[e];
        else if (e < 40)             v = vdb1[e - 20];
        else if (e < 60)             v = vdW2[e - 40];
        else if (e >= 64 && e < 84)  v = vvW1[e - 64];
        else if (e >= 84 && e < 104) v = vvb1[e - 84];
        else if (e >= 104 && e < 124)v = vvW2[e - 104];
        else if (e == 124)           v = vdb2[0];
        else if (e == 125)           v = vvb2[0];
        VW[e] = v;
    }

    // ---- stage P1 / hedge-L1 packed weight tables --------------------------
    if (tid < 16) {
        const int cc = tid;
        uint4 A, B, C, D;
#pragma unroll
        for (int e2 = 0; e2 < 4; e2++) {
            const int k0 = 8 * cc + 2 * e2, k1 = k0 + 1;
            const float a0 = k0 < 100 ? svW1[k0] : 0.f,        a1 = k1 < 100 ? svW1[k1] : 0.f;
            const float b0 = k0 < 100 ? svW1[100 + k0] : 0.f,  b1 = k1 < 100 ? svW1[100 + k1] : 0.f;
            const float c0 = k0 < 100 ? svW1[200 + k0] : 0.f,  c1 = k1 < 100 ? svW1[200 + k1] : 0.f;
            const float d0 = k0 < 100 ? svb1[k0] : 0.f,        d1 = k1 < 100 ? svb1[k1] : 0.f;
            (&A.x)[e2] = bf16rne(a0) | (bf16rne(a1) << 16);
            (&B.x)[e2] = bf16rne(b0) | (bf16rne(b1) << 16);
            (&C.x)[e2] = bf16rne(c0) | (bf16rne(c1) << 16);
            (&D.x)[e2] = bf16rne(d0) | (bf16rne(d1) << 16);
        }
        W1T[cc][0] = A; W1T[cc][1] = B; W1T[cc][2] = C; W1T[cc][3] = D;
    } else if (tid >= 64 && tid < 80) {
        const int mm = (tid - 64) >> 2, qq = (tid - 64) & 3;
        uint4 T, Sv, Bb;
#pragma unroll
        for (int e2 = 0; e2 < 4; e2++) {
            const int j0 = 8 * qq + 2 * e2, j1 = j0 + 1;
            const float t0v = j0 < 20 ? vhW1[mm * 40 + j0] : 0.f;
            const float t1v = j1 < 20 ? vhW1[mm * 40 + j1] : 0.f;
            const float s0v = j0 < 20 ? vhW1[mm * 40 + 20 + j0] : 0.f;
            const float s1v = j1 < 20 ? vhW1[mm * 40 + 20 + j1] : 0.f;
            const float b0v = j0 < 20 ? vhb1[mm * 20 + j0] : 0.f;
            const float b1v = j1 < 20 ? vhb1[mm * 20 + j1] : 0.f;
            (&T.x)[e2]  = bf16rne(t0v) | (bf16rne(t1v) << 16);
            (&Sv.x)[e2] = bf16rne(s0v) | (bf16rne(s1v) << 16);
            (&Bb.x)[e2] = bf16rne(b0v) | (bf16rne(b1v) << 16);
        }
        WH1[mm][qq][0] = T; WH1[mm][qq][1] = Sv; WH1[mm][qq][2] = Bb;
    }

    // ---- uniform setup -----------------------------------------------------
    const float rate  = ratep[0];
    const float S0    = S0p[0];
    const float rho_t = tanhf(rhop[0]);
    const float srho  = sqrtf(1.f - rho_t * rho_t);
    const float b3    = svb3[0];
    int matr[4];
#pragma unroll
    for (int k = 0; k < 4; k++) matr[k] = mats[k];

    const int m0 = 16 * (w & 3);
    const int ng = w >> 2;
    const int m  = w >> 2;
    const int pt = w & 3;

    // ---- MFMA B-fragments in registers (AGPR-resident) ---------------------
    bf16x8 Bf[4][2];
#pragma unroll
    for (int c = 0; c < 4; c++)
#pragma unroll
        for (int st = 0; st < 2; st++) {
            U8 t;
#pragma unroll
            for (int e2 = 0; e2 < 4; e2++) {
                const int k0 = 32 * c + 8 * quad + 2 * e2;
                const int j  = 32 * ng + 16 * st + col;
                const float v0 = (k0     < 100 && j < 100) ? svW2[k0 * 100 + j]       : 0.f;
                const float v1 = (k0 + 1 < 100 && j < 100) ? svW2[(k0 + 1) * 100 + j] : 0.f;
                (&t.u.x)[e2] = bf16rne(v0) | (bf16rne(v1) << 16);
            }
            Bf[c][st] = t.v;
        }
    const int jA = 32 * ng + col, jB = jA + 16;
    const float2 bw0 = make_float2(jA < 100 ? svb2[jA] : 0.f, jA < 100 ? svW3[jA] : 0.f);
    const float2 bw1 = make_float2(jB < 100 ? svb2[jB] : 0.f, jB < 100 ? svW3[jB] : 0.f);

    bf16x8 Bh[2];
#pragma unroll
    for (int st = 0; st < 2; st++) {
        U8 t;
#pragma unroll
        for (int e2 = 0; e2 < 4; e2++) {
            const int k0 = 8 * quad + 2 * e2, k1 = k0 + 1;
            const int s  = 16 * st + col;
            const float v0 = (k0 < 20 && s < 21) ? vhW2[m * 420 + k0 * 21 + s] : 0.f;
            const float v1 = (k1 < 20 && s < 21) ? vhW2[m * 420 + k1 * 21 + s] : 0.f;
            (&t.u.x)[e2] = bf16rne(v0) | (bf16rne(v1) << 16);
        }
        Bh[st] = t.v;
    }
    const int sA = col, sB = 16 + col;
    const float b2s0 = vhb2[m * 21 + sA];
    const float b2s1 = (sB < 21) ? vhb2[m * 21 + sB] : 0.f;
    const float K0   = strikesg[sA];
    const float K1   = (sB < 21) ? strikesg[sB] : 1e30f;

    // ---- per-path state ----------------------------------------------------
    float Slog = __logf(S0);
    float S    = __expf(Slog);
    float V    = (1.f / (1.f + __expf(-v0p[0]))) * 0.5f;
    f32x4 cv0 = {0.f, 0.f, 0.f, 0.f};
    f32x4 cv1 = {0.f, 0.f, 0.f, 0.f};
    float Slog_prev = 0.f, dS_prev = 0.f, disc1_prev = 1.f, t0_prev = 0.f;
    int   idx_prev = 0;
    bool  im_prev  = false;

    const float* zrow  = z   + (size_t)gpath * NSTEP;
    const float* zzrow = zzg + (size_t)gpath * NSTEP;

    const int pp = 4 * w + quad;
    const int pbase = 16 * pt + 4 * quad;

    __syncthreads();

    auto hedge_step = [&]() {
        if (m >= idx_prev) {
            const uint4 T  = WH1[m][quad][0];
            const uint4 Sw = WH1[m][quad][1];
            const uint4 Bb = WH1[m][quad][2];
            const float slp = __shfl(Slog_prev, 16 * pt + col);
            U8 a;
#pragma unroll
            for (int e2 = 0; e2 < 4; e2++) {
                const unsigned tp = (&T.x)[e2], sq_ = (&Sw.x)[e2], bb = (&Bb.x)[e2];
                const float h0 = fmaxf(t0_prev * blo(tp) + slp * blo(sq_) + blo(bb), 0.f);
                const float h1 = fmaxf(t0_prev * bhi(tp) + slp * bhi(sq_) + bhi(bb), 0.f);
                (&a.u.x)[e2] = bf16rne(h0) | (bf16rne(h1) << 16);
            }
            const f32x4 z4 = {0.f, 0.f, 0.f, 0.f};
            const f32x4 D0 = __builtin_amdgcn_mfma_f32_16x16x32_bf16(a.v, Bh[0], z4, 0, 0, 0);
            const f32x4 D1 = __builtin_amdgcn_mfma_f32_16x16x32_bf16(a.v, Bh[1], z4, 0, 0, 0);
            float dsr[4];
#pragma unroll
            for (int r = 0; r < 4; r++) dsr[r] = __shfl(dS_prev, pbase + r);
#pragma unroll
            for (int r = 0; r < 4; r++) {
                cv0[r] += sp(D0[r] + b2s0) * dsr[r];
                cv1[r] += sp(D1[r] + b2s1) * dsr[r];
            }
            if (im_prev && m == idx_prev) {
                float s0 = 0.f, q0 = 0.f, s1 = 0.f, q1 = 0.f;
#pragma unroll
                for (int r = 0; r < 4; r++) {
                    const float Sp = __shfl(S, pbase + r);
                    const float p0 = disc1_prev * fmaxf(Sp - K0, 0.f) - cv0[r];
                    const float p1 = disc1_prev * fmaxf(Sp - K1, 0.f) - cv1[r];
                    s0 += p0; q0 += p0 * p0;
                    s1 += p1; q1 += p1 * p1;
                }
                s0 += __shfl_xor(s0, 16); s0 += __shfl_xor(s0, 32);
                q0 += __shfl_xor(q0, 16); q0 += __shfl_xor(q0, 32);
                s1 += __shfl_xor(s1, 16); s1 += __shfl_xor(s1, 32);
                q1 += __shfl_xor(q1, 16); q1 += __shfl_xor(q1, 32);
                if (quad == 0) {
                    PSs[pt][col] = s0;  PSq[pt][col] = q0;
                    if (col < 5) { PSs[pt][16 + col] = s1;  PSq[pt][16 + col] = q1; }
                }
            }
        }
    };

    auto ps_reduce = [&]() {
        if (w == 0 && im_prev) {
            const int s = lane & 31;
            if (s < 21) {
                const float* src = (lane >= 32) ? &PSq[0][0] : &PSs[0][0];
                const float acc = src[s] + src[32 + s] + src[64 + s] + src[96 + s];
                float* dst = (lane >= 32) ? psq : psum;
                dst[(idx_prev * 21 + s) * NGROUP + blockIdx.x] = acc;
            }
        }
    };

    for (int i = 0; i < NSTEP; i++) {
        const float zi  = zrow[i];
        const float zzi = zzrow[i];

        const float t0    = (float)i       * (1.f / 365.f);
        const float t1    = (float)(i + 1) * (1.f / 365.f);
        const float h     = t1 - t0;
        const float sqh   = sqrtf(h);
        const float disc0 = __expf(-rate * t0);
        const float disc1 = __expf(-rate * t1);
        const int   day   = i + 1;
        const int   idx   = (day > matr[0]) + (day > matr[1]) + (day > matr[2]);
        const bool  im    = (day == matr[idx]);

        // ===== Region 1 =====================================================
        {
            const uint4 A  = W1T[col][0];
            const uint4 Bv = W1T[col][1];
            const uint4 C  = W1T[col][2];
            const uint4 D  = W1T[col][3];
            const float slp = __shfl(Slog, pp);
            const float vp  = __shfl(V, pp);
            uint4 o;
#pragma unroll
            for (int e2 = 0; e2 < 4; e2++) {
                const unsigned ua = (&A.x)[e2], ub = (&Bv.x)[e2], uc = (&C.x)[e2], ud = (&D.x)[e2];
                const float h0 = fmaxf(t0 * blo(ua) + slp * blo(ub) + vp * blo(uc) + blo(ud), 0.f);
                const float h1 = fmaxf(t0 * bhi(ua) + slp * bhi(ub) + vp * bhi(uc) + bhi(ud), 0.f);
                (&o.x)[e2] = bf16rne(h0) | (bf16rne(h1) << 16);
            }
            *reinterpret_cast<uint4*>(H1 + pp * KSTR + col * 8) = o;
        }
        if (i > 0) hedge_step();
        if (w == 14) {
            float a2 = 0.f;
#pragma unroll
            for (int q5 = 0; q5 < 5; q5++) {
                const float4 w1 = *reinterpret_cast<const float4*>(VW + 4 * q5);
                const float4 b1 = *reinterpret_cast<const float4*>(VW + 20 + 4 * q5);
                const float4 w2 = *reinterpret_cast<const float4*>(VW + 40 + 4 * q5);
                a2 += fmaxf(V * w1.x + b1.x, 0.f) * w2.x;
                a2 += fmaxf(V * w1.y + b1.y, 0.f) * w2.y;
                a2 += fmaxf(V * w1.z + b1.z, 0.f) * w2.z;
                a2 += fmaxf(V * w1.w + b1.w, 0.f) * w2.w;
            }
            VDl[i & 1][lane] = a2;
        }
        if (w == 15) {
            float a2 = 0.f;
#pragma unroll
            for (int q5 = 0; q5 < 5; q5++) {
                const float4 w1 = *reinterpret_cast<const float4*>(VW + 64 + 4 * q5);
                const float4 b1 = *reinterpret_cast<const float4*>(VW + 84 + 4 * q5);
                const float4 w2 = *reinterpret_cast<const float4*>(VW + 104 + 4 * q5);
                a2 += fmaxf(V * w1.x + b1.x, 0.f) * w2.x;
                a2 += fmaxf(V * w1.y + b1.y, 0.f) * w2.y;
                a2 += fmaxf(V * w1.z + b1.z, 0.f) * w2.z;
                a2 += fmaxf(V * w1.w + b1.w, 0.f) * w2.w;
            }
            VVl[i & 1][lane] = a2;
        }
        __syncthreads();

        // ===== Region 2 =====================================================
        {
            f32x4 d0 = {0.f, 0.f, 0.f, 0.f};
            f32x4 d1 = {0.f, 0.f, 0.f, 0.f};
#pragma unroll
            for (int c = 0; c < 4; c++) {
                const bf16x8 afr = *reinterpret_cast<const bf16x8*>(H1 + (m0 + col) * KSTR + 8 * quad + 32 * c);
                d0 = __builtin_amdgcn_mfma_f32_16x16x32_bf16(afr, Bf[c][0], d0, 0, 0, 0);
                d1 = __builtin_amdgcn_mfma_f32_16x16x32_bf16(afr, Bf[c][1], d1, 0, 0, 0);
            }
            float sr[4];
#pragma unroll
            for (int r = 0; r < 4; r++)
                sr[r] = fmaxf(d0[r] + bw0.x, 0.f) * bw0.y + fmaxf(d1[r] + bw1.x, 0.f) * bw1.y;
#pragma unroll
            for (int msk = 1; msk <= 8; msk <<= 1) {
                sr[0] += __shfl_xor(sr[0], msk);
                sr[1] += __shfl_xor(sr[1], msk);
                sr[2] += __shfl_xor(sr[2], msk);
                sr[3] += __shfl_xor(sr[3], msk);
            }
            const float outv = (col == 0) ? sr[0] : (col == 1) ? sr[1]
                             : (col == 2) ? sr[2] : sr[3];
            if (col < 4)
                RED[(m0 + 4 * quad + col) * 4 + ng] = outv;
        }
        ps_reduce();
        __syncthreads();

        // ===== Region 3 =====================================================
        {
            const float4 rr = *reinterpret_cast<const float4*>(RED + lane * 4);
            const float pout = (rr.x + rr.y) + (rr.z + rr.w);
            const float pd = sp(pout + b3);
            const float vdv = VDl[i & 1][lane] + VW[124];
            const float vvv = sp(VVl[i & 1][lane] + VW[125]);
            const float dW = sqh * zi;
            const float dB = rho_t * dW + srho * sqh * zzi;
            const float Vn = V + vdv * h + vvv * dB;
            const float drift   = rate - 0.5f * pd * pd;
            const float diff    = pd * dW;
            const float drift_c = 1.f + fabsf(drift) * sqh;
            const float diff_c  = 1.f + fabsf(pd) * sqh;
            const float Sln = Slog + __fdividef(drift * h, drift_c) + __fdividef(diff, diff_c);
            const float Sn  = __expf(Sln);
            const float dS  = disc1 * Sn - disc0 * S;
            Slog_prev = Slog; dS_prev = dS; disc1_prev = disc1; t0_prev = t0;
            idx_prev = idx; im_prev = im;
            Slog = Sln; S = Sn; V = Vn;
        }
    }

    hedge_step();
    __syncthreads();
    ps_reduce();
}

__global__ void lsv_finalize(const float* __restrict__ psum,
                             const float* __restrict__ psq,
                             float* __restrict__ out)
{
    const int t = blockIdx.x * blockDim.x + threadIdx.x;
    if (t >= NPAIR) return;
    float s = 0.f, q = 0.f;
    for (int b = 0; b < NGROUP; b++) {
        s += psum[t * NGROUP + b];
        q += psq [t * NGROUP + b];
    }
    const float mean = s * (1.0f / (float)MC);
    const float var  = (q - (float)MC * mean * mean) * (1.0f / (float)(MC - 1));
    out[t]         = mean;
    out[NPAIR + t] = var;
}

extern "C" void kernel_launch(void* const* d_in, const int* in_sizes, int n_in,
                              void* d_out, int out_size, void* d_ws, size_t ws_size,
                              hipStream_t stream)
{
    const float* S0    = (const float*)d_in[0];
    const float* rate  = (const float*)d_in[1];
    const float* z     = (const float*)d_in[2];
    const float* zz    = (const float*)d_in[3];
    const float* strikes = (const float*)d_in[5];
    const float* v0    = (const float*)d_in[6];
    const float* rho   = (const float*)d_in[7];
    const float* svW1  = (const float*)d_in[8];
    const float* svb1  = (const float*)d_in[9];
    const float* svW2  = (const float*)d_in[10];
    const float* svb2  = (const float*)d_in[11];
    const float* svW3  = (const float*)d_in[12];
    const float* svb3  = (const float*)d_in[13];
    const float* vhW1  = (const float*)d_in[14];
    const float* vhb1  = (const float*)d_in[15];
    const float* vhW2  = (const float*)d_in[16];
    const float* vhb2  = (const float*)d_in[17];
    const float* vdW1  = (const float*)d_in[18];
    const float* vdb1  = (const float*)d_in[19];
    const float* vdW2  = (const float*)d_in[20];
    const float* vdb2  = (const float*)d_in[21];
    const float* vvW1  = (const float*)d_in[22];
    const float* vvb1  = (const float*)d_in[23];
    const float* vvW2  = (const float*)d_in[24];
    const float* vvb2  = (const float*)d_in[25];
    const int*   mats  = (const int*)d_in[26];

    float* psum = (float*)d_ws;
    float* psq  = psum + NPAIR * NGROUP;

    hipLaunchKernelGGL(lsv_sim, dim3(NGROUP), dim3(BLOCK), 0, stream,
                       S0, rate, z, zz, strikes, v0, rho,
                       svW1, svb1, svW2, svb2, svW3, svb3,
                       vhW1, vhb1, vhW2, vhb2,
                       vdW1, vdb1, vdW2, vdb2,
                       vvW1, vvb1, vvW2, vvb2,
                       mats, psum, psq);

    hipLaunchKernelGGL(lsv_finalize, dim3(1), dim3(128), 0, stream,
                       psum, psq, (float*)d_out);
}

// Round 6
// 434.427 us; speedup vs baseline: 14.6926x; 1.1885x over previous
//
#include <hip/hip_runtime.h>
#include <hip/hip_bf16.h>
#include <math.h>

// ---------------------------------------------------------------------------
// LSV Monte Carlo, round 6.
// R5 was VALU/LDS-issue bound with 2.5e7 bank conflicts. Changes:
//  * GEMMs flipped: A = invariant weights (AGPR), B = per-step activations.
//    D gets col=path -> per-lane epilogue; reduction = 2 butterflies not 4;
//    hedge needs 1 dS/S shuffle not 4.
//  * H1 stored as [kchunk][path][16B] chunks: P1 writes and B-frag reads are
//    lane-linear (8 lanes -> 128 contiguous bytes) -> conflict-free.
//  * VALU-side weights (svW1, hedge L1, biases) in fp32 LDS broadcast tables;
//    bf16 packing via v_cvt_pk_bf16_f32 (__float22bfloat162_rn).
// ---------------------------------------------------------------------------

#define MC      16384
#define NSTEP   96
#define BLOCK   1024
#define NGROUP  256
#define NPAIR   84

typedef short bf16x8 __attribute__((ext_vector_type(8)));
typedef float f32x4  __attribute__((ext_vector_type(4)));

union U8 { uint4 u; bf16x8 v; };
union BF2U { __hip_bfloat162 b; unsigned u; };

__device__ __forceinline__ unsigned bf16rne(float x) {   // setup-time only
    unsigned u = __float_as_uint(x);
    return (u + 0x7FFFu + ((u >> 16) & 1u)) >> 16;
}
__device__ __forceinline__ unsigned pk2(float lo, float hi) {
    BF2U t; t.b = __float22bfloat162_rn(make_float2(lo, hi));
    return t.u;
}
__device__ __forceinline__ float sp(float x) {
    return fmaxf(x, 0.f) + __logf(1.f + __expf(-fabsf(x)));
}

__global__ __launch_bounds__(BLOCK, 4)
void lsv_sim(const float* __restrict__ S0p,   const float* __restrict__ ratep,
             const float* __restrict__ z,     const float* __restrict__ zzg,
             const float* __restrict__ strikesg,
             const float* __restrict__ v0p,   const float* __restrict__ rhop,
             const float* __restrict__ svW1,  const float* __restrict__ svb1,
             const float* __restrict__ svW2,  const float* __restrict__ svb2,
             const float* __restrict__ svW3,  const float* __restrict__ svb3,
             const float* __restrict__ vhW1,  const float* __restrict__ vhb1,
             const float* __restrict__ vhW2,  const float* __restrict__ vhb2,
             const float* __restrict__ vdW1,  const float* __restrict__ vdb1,
             const float* __restrict__ vdW2,  const float* __restrict__ vdb2,
             const float* __restrict__ vvW1,  const float* __restrict__ vvb1,
             const float* __restrict__ vvW2,  const float* __restrict__ vvb2,
             const int*   __restrict__ mats,
             float* __restrict__ psum, float* __restrict__ psq)
{
    __shared__ __align__(16) unsigned short H1c[16 * 64 * 8]; // 16 KB [kchunk][path][8]
    __shared__ __align__(16) float W1f[16 * 32];              // 2 KB  [kc]{wa8,wb8,wc8,bias8}
    __shared__ __align__(16) float WH1f[16 * 32];             // 2 KB  [hm*4+quad]{wt8,ws8,bb8,pad8}
    __shared__ __align__(16) float B2T[128], W3T[128];        // 1 KB
    __shared__ float RED[64 * 4];                             // 1 KB [path][jg]
    __shared__ float VDl[2][64], VVl[2][64];                  // 1 KB
    __shared__ float PSs[4][32], PSq[4][32];                  // 1 KB
    __shared__ float VW[128];                                 // 512 B

    const int tid  = threadIdx.x;
    const int lane = tid & 63;
    const int w    = __builtin_amdgcn_readfirstlane(tid >> 6);
    const int quad = lane >> 4;
    const int col  = lane & 15;
    const int gpath = blockIdx.x * 64 + lane;

    const int pt = w & 3;      // path tile (both GEMMs)
    const int jg = w >> 2;     // main: j-group 0..3 (j-tiles 2jg, 2jg+1)
    const int hm = w >> 2;     // hedge: maturity

    // ---- stage LDS tables --------------------------------------------------
    for (int e = tid; e < 128; e += BLOCK) {
        float v = 0.f;
        if      (e < 20)             v = vdW1[e];
        else if (e < 40)             v = vdb1[e - 20];
        else if (e < 60)             v = vdW2[e - 40];
        else if (e >= 64 && e < 84)  v = vvW1[e - 64];
        else if (e >= 84 && e < 104) v = vvb1[e - 84];
        else if (e >= 104 && e < 124)v = vvW2[e - 104];
        else if (e == 124)           v = vdb2[0];
        else if (e == 125)           v = vvb2[0];
        VW[e] = v;
        B2T[e] = (e < 100) ? svb2[e] : 0.f;
        W3T[e] = (e < 100) ? svW3[e] : 0.f;
    }
    for (int e = tid; e < 512; e += BLOCK) {       // W1f
        const int kc2 = e >> 5, r5 = e & 31, grp = r5 >> 3, kk = kc2 * 8 + (r5 & 7);
        float v = 0.f;
        if (kk < 100) v = (grp == 0) ? svW1[kk] : (grp == 1) ? svW1[100 + kk]
                        : (grp == 2) ? svW1[200 + kk] : svb1[kk];
        W1f[e] = v;
    }
    for (int e = tid; e < 512; e += BLOCK) {       // WH1f
        const int hq = e >> 5, r5 = e & 31, grp = r5 >> 3;
        const int hmm = hq >> 2, qq = hq & 3;
        const int j = qq * 8 + (r5 & 7);
        float v = 0.f;
        if (j < 20 && grp < 3)
            v = (grp == 0) ? vhW1[hmm * 40 + j] : (grp == 1) ? vhW1[hmm * 40 + 20 + j]
                                                : vhb1[hmm * 20 + j];
        WH1f[e] = v;
    }

    // ---- uniform setup -----------------------------------------------------
    const float rate  = ratep[0];
    const float S0    = S0p[0];
    const float rho_t = tanhf(rhop[0]);
    const float srho  = sqrtf(1.f - rho_t * rho_t);
    const float b3    = svb3[0];
    int matr[4];
#pragma unroll
    for (int k = 0; k < 4; k++) matr[k] = mats[k];

    // ---- invariant A-fragments (weights) -> AGPRs --------------------------
    // main: A[m=j][k], j = (2jg+t)*16 + col, k = 32c + 8quad + e
    bf16x8 Af[4][2];
#pragma unroll
    for (int c = 0; c < 4; c++)
#pragma unroll
        for (int t = 0; t < 2; t++) {
            U8 tt;
#pragma unroll
            for (int e2 = 0; e2 < 4; e2++) {
                const int k0 = 32 * c + 8 * quad + 2 * e2;
                const int j  = (2 * jg + t) * 16 + col;
                const float v0 = (k0     < 100 && j < 100) ? svW2[k0 * 100 + j]       : 0.f;
                const float v1 = (k0 + 1 < 100 && j < 100) ? svW2[(k0 + 1) * 100 + j] : 0.f;
                (&tt.u.x)[e2] = bf16rne(v0) | (bf16rne(v1) << 16);
            }
            Af[c][t] = tt.v;
        }
    // hedge: A[m=s][k=j], s = st*16 + col, j = 8quad + e
    bf16x8 Ah[2];
#pragma unroll
    for (int st = 0; st < 2; st++) {
        U8 tt;
#pragma unroll
        for (int e2 = 0; e2 < 4; e2++) {
            const int j0 = 8 * quad + 2 * e2, j1 = j0 + 1;
            const int s  = st * 16 + col;
            const float v0 = (j0 < 20 && s < 21) ? vhW2[hm * 420 + j0 * 21 + s] : 0.f;
            const float v1 = (j1 < 20 && s < 21) ? vhW2[hm * 420 + j1 * 21 + s] : 0.f;
            (&tt.u.x)[e2] = bf16rne(v0) | (bf16rne(v1) << 16);
        }
        Ah[st] = tt.v;
    }
    // hedge per-lane D-row constants: s0 = quad*4+r (<16), s1 = 16+quad*4+r
    float b2h0[4], b2h1[4], K0a[4], K1a[4];
#pragma unroll
    for (int r = 0; r < 4; r++) {
        const int s0 = quad * 4 + r, s1 = 16 + quad * 4 + r;
        b2h0[r] = vhb2[hm * 21 + s0];
        K0a[r]  = strikesg[s0];
        b2h1[r] = (s1 < 21) ? vhb2[hm * 21 + s1] : 0.f;
        K1a[r]  = (s1 < 21) ? strikesg[s1] : 1e30f;
    }

    // ---- per-path state (lane = path, redundant across waves) --------------
    float Slog = __logf(S0);
    float S    = __expf(Slog);
    float V    = (1.f / (1.f + __expf(-v0p[0]))) * 0.5f;
    f32x4 cv0 = {0.f, 0.f, 0.f, 0.f};
    f32x4 cv1 = {0.f, 0.f, 0.f, 0.f};
    float Slog_prev = 0.f, dS_prev = 0.f, disc1_prev = 1.f, t0_prev = 0.f;
    int   idx_prev = 0;
    bool  im_prev  = false;

    const float* zrow  = z   + (size_t)gpath * NSTEP;
    const float* zzrow = zzg + (size_t)gpath * NSTEP;

    const int path = pt * 16 + col;        // P1/B-frag path of this thread
    const int kc   = jg * 4 + quad;        // P1 k-chunk of this thread

    __syncthreads();

    auto hedge_step = [&]() {
        if (hm >= idx_prev) {
            const float slp = __shfl(Slog_prev, path);
            U8 b;
#pragma unroll
            for (int hh = 0; hh < 2; hh++) {
                const float* Wp = WH1f + (hm * 4 + quad) * 32 + hh * 4;
                const float4 wt4 = *reinterpret_cast<const float4*>(Wp);
                const float4 ws4 = *reinterpret_cast<const float4*>(Wp + 8);
                const float4 bb4 = *reinterpret_cast<const float4*>(Wp + 16);
                const float x0 = fmaxf(bb4.x + t0_prev * wt4.x + slp * ws4.x, 0.f);
                const float x1 = fmaxf(bb4.y + t0_prev * wt4.y + slp * ws4.y, 0.f);
                const float x2 = fmaxf(bb4.z + t0_prev * wt4.z + slp * ws4.z, 0.f);
                const float x3 = fmaxf(bb4.w + t0_prev * wt4.w + slp * ws4.w, 0.f);
                (&b.u.x)[2 * hh]     = pk2(x0, x1);
                (&b.u.x)[2 * hh + 1] = pk2(x2, x3);
            }
            const f32x4 z4 = {0.f, 0.f, 0.f, 0.f};
            const f32x4 D0 = __builtin_amdgcn_mfma_f32_16x16x32_bf16(Ah[0], b.v, z4, 0, 0, 0);
            const f32x4 D1 = __builtin_amdgcn_mfma_f32_16x16x32_bf16(Ah[1], b.v, z4, 0, 0, 0);
            const float dsP = __shfl(dS_prev, path);
#pragma unroll
            for (int r = 0; r < 4; r++) {
                cv0[r] += sp(D0[r] + b2h0[r]) * dsP;
                cv1[r] += sp(D1[r] + b2h1[r]) * dsP;
            }
            if (im_prev && hm == idx_prev) {
                const float Sp = __shfl(S, path);
                float p0[4], q0[4], p1[4], q1[4];
#pragma unroll
                for (int r = 0; r < 4; r++) {
                    p0[r] = disc1_prev * fmaxf(Sp - K0a[r], 0.f) - cv0[r];
                    p1[r] = disc1_prev * fmaxf(Sp - K1a[r], 0.f) - cv1[r];
                    q0[r] = p0[r] * p0[r];
                    q1[r] = p1[r] * p1[r];
                }
#pragma unroll
                for (int o = 1; o <= 8; o <<= 1) {
#pragma unroll
                    for (int r = 0; r < 4; r++) {
                        p0[r] += __shfl_xor(p0[r], o);
                        q0[r] += __shfl_xor(q0[r], o);
                        p1[r] += __shfl_xor(p1[r], o);
                        q1[r] += __shfl_xor(q1[r], o);
                    }
                }
                if (col == 0) {
#pragma unroll
                    for (int r = 0; r < 4; r++) {
                        const int s0 = quad * 4 + r, s1 = 16 + quad * 4 + r;
                        PSs[pt][s0] = p0[r];  PSq[pt][s0] = q0[r];
                        if (s1 < 21) { PSs[pt][s1] = p1[r];  PSq[pt][s1] = q1[r]; }
                    }
                }
            }
        }
    };

    auto ps_reduce = [&]() {
        if (w == 0 && im_prev) {
            const int s = lane & 31;
            if (s < 21) {
                const float* src = (lane >= 32) ? &PSq[0][0] : &PSs[0][0];
                const float acc = src[s] + src[32 + s] + src[64 + s] + src[96 + s];
                float* dst = (lane >= 32) ? psq : psum;
                dst[(idx_prev * 21 + s) * NGROUP + blockIdx.x] = acc;
            }
        }
    };

    for (int i = 0; i < NSTEP; i++) {
        const float zi  = zrow[i];
        const float zzi = zzrow[i];

        const float t0    = (float)i       * (1.f / 365.f);
        const float t1    = (float)(i + 1) * (1.f / 365.f);
        const float h     = t1 - t0;
        const float sqh   = sqrtf(h);
        const float disc0 = __expf(-rate * t0);
        const float disc1 = __expf(-rate * t1);
        const int   day   = i + 1;
        const int   idx   = (day > matr[0]) + (day > matr[1]) + (day > matr[2]);
        const bool  im    = (day == matr[idx]);

        // ===== Region 1: P1 h1 chunk | lagged hedge | vd/vv nets ============
        {
            const float slp = __shfl(Slog, path);
            const float vp  = __shfl(V, path);
            const float* Wp = W1f + kc * 32;
            uint4 o;
#pragma unroll
            for (int hh = 0; hh < 2; hh++) {
                const float4 a4 = *reinterpret_cast<const float4*>(Wp + hh * 4);
                const float4 b4 = *reinterpret_cast<const float4*>(Wp + 8 + hh * 4);
                const float4 c4 = *reinterpret_cast<const float4*>(Wp + 16 + hh * 4);
                const float4 d4 = *reinterpret_cast<const float4*>(Wp + 24 + hh * 4);
                const float x0 = fmaxf(d4.x + t0 * a4.x + slp * b4.x + vp * c4.x, 0.f);
                const float x1 = fmaxf(d4.y + t0 * a4.y + slp * b4.y + vp * c4.y, 0.f);
                const float x2 = fmaxf(d4.z + t0 * a4.z + slp * b4.z + vp * c4.z, 0.f);
                const float x3 = fmaxf(d4.w + t0 * a4.w + slp * b4.w + vp * c4.w, 0.f);
                (&o.x)[2 * hh]     = pk2(x0, x1);
                (&o.x)[2 * hh + 1] = pk2(x2, x3);
            }
            *reinterpret_cast<uint4*>(H1c + (kc * 64 + path) * 8) = o;
        }
        if (i > 0) hedge_step();
        if (w == 14) {
            float a2 = 0.f;
#pragma unroll
            for (int q5 = 0; q5 < 5; q5++) {
                const float4 w1 = *reinterpret_cast<const float4*>(VW + 4 * q5);
                const float4 b1 = *reinterpret_cast<const float4*>(VW + 20 + 4 * q5);
                const float4 w2 = *reinterpret_cast<const float4*>(VW + 40 + 4 * q5);
                a2 += fmaxf(V * w1.x + b1.x, 0.f) * w2.x;
                a2 += fmaxf(V * w1.y + b1.y, 0.f) * w2.y;
                a2 += fmaxf(V * w1.z + b1.z, 0.f) * w2.z;
                a2 += fmaxf(V * w1.w + b1.w, 0.f) * w2.w;
            }
            VDl[i & 1][lane] = a2;
        }
        if (w == 15) {
            float a2 = 0.f;
#pragma unroll
            for (int q5 = 0; q5 < 5; q5++) {
                const float4 w1 = *reinterpret_cast<const float4*>(VW + 64 + 4 * q5);
                const float4 b1 = *reinterpret_cast<const float4*>(VW + 84 + 4 * q5);
                const float4 w2 = *reinterpret_cast<const float4*>(VW + 104 + 4 * q5);
                a2 += fmaxf(V * w1.x + b1.x, 0.f) * w2.x;
                a2 += fmaxf(V * w1.y + b1.y, 0.f) * w2.y;
                a2 += fmaxf(V * w1.z + b1.z, 0.f) * w2.z;
                a2 += fmaxf(V * w1.w + b1.w, 0.f) * w2.w;
            }
            VVl[i & 1][lane] = a2;
        }
        __syncthreads();

        // ===== Region 2: main MFMA (A=W2T inv, B=h1) + per-lane epilogue ====
        {
            f32x4 d0 = {0.f, 0.f, 0.f, 0.f};
            f32x4 d1 = {0.f, 0.f, 0.f, 0.f};
#pragma unroll
            for (int c = 0; c < 4; c++) {
                const bf16x8 b = *reinterpret_cast<const bf16x8*>(
                    H1c + ((quad + 4 * c) * 64 + path) * 8);
                d0 = __builtin_amdgcn_mfma_f32_16x16x32_bf16(Af[c][0], b, d0, 0, 0, 0);
                d1 = __builtin_amdgcn_mfma_f32_16x16x32_bf16(Af[c][1], b, d1, 0, 0, 0);
            }
            const int j0 = (2 * jg) * 16 + quad * 4;
            const float4 b2a = *reinterpret_cast<const float4*>(B2T + j0);
            const float4 w3a = *reinterpret_cast<const float4*>(W3T + j0);
            const float4 b2b = *reinterpret_cast<const float4*>(B2T + j0 + 16);
            const float4 w3b = *reinterpret_cast<const float4*>(W3T + j0 + 16);
            float acc = fmaxf(d0[0] + b2a.x, 0.f) * w3a.x
                      + fmaxf(d0[1] + b2a.y, 0.f) * w3a.y
                      + fmaxf(d0[2] + b2a.z, 0.f) * w3a.z
                      + fmaxf(d0[3] + b2a.w, 0.f) * w3a.w
                      + fmaxf(d1[0] + b2b.x, 0.f) * w3b.x
                      + fmaxf(d1[1] + b2b.y, 0.f) * w3b.y
                      + fmaxf(d1[2] + b2b.z, 0.f) * w3b.z
                      + fmaxf(d1[3] + b2b.w, 0.f) * w3b.w;
            acc += __shfl_xor(acc, 16);
            acc += __shfl_xor(acc, 32);
            if (quad == 0)
                RED[path * 4 + jg] = acc;
        }
        ps_reduce();
        __syncthreads();

        // ===== Region 3: SDE tail (redundant per wave, state in regs) =======
        {
            const float4 rr = *reinterpret_cast<const float4*>(RED + lane * 4);
            const float pout = (rr.x + rr.y) + (rr.z + rr.w);
            const float pd = sp(pout + b3);
            const float vdv = VDl[i & 1][lane] + VW[124];
            const float vvv = sp(VVl[i & 1][lane] + VW[125]);
            const float dW = sqh * zi;
            const float dB = rho_t * dW + srho * sqh * zzi;
            const float Vn = V + vdv * h + vvv * dB;
            const float drift   = rate - 0.5f * pd * pd;
            const float diff    = pd * dW;
            const float drift_c = 1.f + fabsf(drift) * sqh;
            const float diff_c  = 1.f + fabsf(pd) * sqh;
            const float Sln = Slog + __fdividef(drift * h, drift_c) + __fdividef(diff, diff_c);
            const float Sn  = __expf(Sln);
            const float dS  = disc1 * Sn - disc0 * S;
            Slog_prev = Slog; dS_prev = dS; disc1_prev = disc1; t0_prev = t0;
            idx_prev = idx; im_prev = im;
            Slog = Sln; S = Sn; V = Vn;
        }
    }

    hedge_step();
    __syncthreads();
    ps_reduce();
}

__global__ void lsv_finalize(const float* __restrict__ psum,
                             const float* __restrict__ psq,
                             float* __restrict__ out)
{
    const int t = blockIdx.x * blockDim.x + threadIdx.x;
    if (t >= NPAIR) return;
    float s = 0.f, q = 0.f;
    for (int b = 0; b < NGROUP; b++) {
        s += psum[t * NGROUP + b];
        q += psq [t * NGROUP + b];
    }
    const float mean = s * (1.0f / (float)MC);
    const float var  = (q - (float)MC * mean * mean) * (1.0f / (float)(MC - 1));
    out[t]         = mean;
    out[NPAIR + t] = var;
}

extern "C" void kernel_launch(void* const* d_in, const int* in_sizes, int n_in,
                              void* d_out, int out_size, void* d_ws, size_t ws_size,
                              hipStream_t stream)
{
    const float* S0    = (const float*)d_in[0];
    const float* rate  = (const float*)d_in[1];
    const float* z     = (const float*)d_in[2];
    const float* zz    = (const float*)d_in[3];
    const float* strikes = (const float*)d_in[5];
    const float* v0    = (const float*)d_in[6];
    const float* rho   = (const float*)d_in[7];
    const float* svW1  = (const float*)d_in[8];
    const float* svb1  = (const float*)d_in[9];
    const float* svW2  = (const float*)d_in[10];
    const float* svb2  = (const float*)d_in[11];
    const float* svW3  = (const float*)d_in[12];
    const float* svb3  = (const float*)d_in[13];
    const float* vhW1  = (const float*)d_in[14];
    const float* vhb1  = (const float*)d_in[15];
    const float* vhW2  = (const float*)d_in[16];
    const float* vhb2  = (const float*)d_in[17];
    const float* vdW1  = (const float*)d_in[18];
    const float* vdb1  = (const float*)d_in[19];
    const float* vdW2  = (const float*)d_in[20];
    const float* vdb2  = (const float*)d_in[21];
    const float* vvW1  = (const float*)d_in[22];
    const float* vvb1  = (const float*)d_in[23];
    const float* vvW2  = (const float*)d_in[24];
    const float* vvb2  = (const float*)d_in[25];
    const int*   mats  = (const int*)d_in[26];

    float* psum = (float*)d_ws;
    float* psq  = psum + NPAIR * NGROUP;

    hipLaunchKernelGGL(lsv_sim, dim3(NGROUP), dim3(BLOCK), 0, stream,
                       S0, rate, z, zz, strikes, v0, rho,
                       svW1, svb1, svW2, svb2, svW3, svb3,
                       vhW1, vhb1, vhW2, vhb2,
                       vdW1, vdb1, vdW2, vdb2,
                       vvW1, vvb1, vvW2, vvb2,
                       mats, psum, psq);

    hipLaunchKernelGGL(lsv_finalize, dim3(1), dim3(128), 0, stream,
                       psum, psq, (float*)d_out);
}